// Round 7
// baseline (424.826 us; speedup 1.0000x reference)
//
#include <hip/hip_runtime.h>
#include <hip/hip_bf16.h>

// Causal MHA forward, B=4 T=2048 C=1024 H=16 D=64. fp32 in/out, bf16 MFMA inside.
// Round 6: attn is BARRIER-FREE. Each wave owns 32 q-rows and loads its MFMA
// K/V B-fragments directly global->VGPR (no LDS staging, no DMA, no
// __syncthreads -> no vmcnt(0) drain coupling). K frags register-double-
// buffered via named vars + manual 2x unroll (r3 spill trap avoided).
// Only P round-trips through (wave-private, padded) LDS for the C->A layout
// transform. L1/L2 serve the 4-waves-per-tile re-reads.

#define Bsz 4
#define Tsz 2048
#define Csz 1024
#define Hn  16
#define Dh  64

typedef unsigned short u16;
typedef __attribute__((ext_vector_type(8))) short bf16x8;   // 8 bf16 = 4 VGPRs
typedef __attribute__((ext_vector_type(4))) float f32x4;
typedef __attribute__((ext_vector_type(4))) unsigned int u32x4;
typedef __attribute__((ext_vector_type(2))) unsigned int u32x2;

__device__ __forceinline__ u16 f2b(float f) {
  __hip_bfloat16 h = __float2bfloat16(f);
  return *reinterpret_cast<u16*>(&h);
}

// async global->LDS, 16B per lane; lds base must be wave-uniform (lane*16 implicit)
__device__ __forceinline__ void gld_lds16(const void* g, void* lds) {
  __builtin_amdgcn_global_load_lds(
      (const __attribute__((address_space(1))) unsigned int*)g,
      (__attribute__((address_space(3))) unsigned int*)lds, 16, 0, 0);
}

// ---------------- fp32 -> bf16 elementwise (8 elems/thread) ----------------
__global__ __launch_bounds__(256) void cvt_f32_bf16(const float* __restrict__ in,
                                                    u16* __restrict__ out) {
  size_t i = ((size_t)blockIdx.x * 256 + threadIdx.x) * 8;
  f32x4 a = *(const f32x4*)(in + i);
  f32x4 b = *(const f32x4*)(in + i + 4);
  u16 r[8];
#pragma unroll
  for (int j = 0; j < 4; ++j) { r[j] = f2b(a[j]); r[4 + j] = f2b(b[j]); }
  *(u32x4*)(out + i) = *(const u32x4*)r;
}

// ---------------- fp32 (R,C) -> bf16 transposed (C,R) ----------------
__global__ __launch_bounds__(256) void cvt_transpose(const float* __restrict__ in,
                                                     u16* __restrict__ out,
                                                     int R, int C) {
  __shared__ u16 tile[64 * 66];
  const int r0 = blockIdx.x * 64, c0 = blockIdx.y * 64;
  const int tid = threadIdx.x;
#pragma unroll
  for (int i = 0; i < 16; ++i) {
    int idx = i * 256 + tid;
    int r = idx >> 6, c = idx & 63;
    tile[r * 66 + c] = f2b(in[(size_t)(r0 + r) * C + (c0 + c)]);
  }
  __syncthreads();
#pragma unroll
  for (int i = 0; i < 16; ++i) {
    int idx = i * 256 + tid;
    int c = idx >> 6, r = idx & 63;
    out[(size_t)(c0 + c) * R + (r0 + r)] = tile[r * 66 + c];
  }
}

// ---------------- 128x128 GEMM core: C[m][n] = sum_k A[m][k]*Bt[n][k], K=1024 ----------------
__device__ __forceinline__ void gemm_tile_acc(const u16* __restrict__ A,
                                              const u16* __restrict__ Bt,
                                              int m0, int n0,
                                              u16* Alds, u16* Blds,
                                              f32x4 acc[4][4]) {
  const int tid = threadIdx.x;
  const int w = tid >> 6, lane = tid & 63;
  const int wm = w & 1, wn = w >> 1;
  const int col = lane & 15, quad = lane >> 4;
  const int lrow = lane >> 2;          // 0..15 within a 16-row group
  const int kseg = (lane & 3) * 8;     // 0,8,16,24
#pragma unroll
  for (int mt = 0; mt < 4; ++mt)
#pragma unroll
    for (int nt = 0; nt < 4; ++nt)
      acc[mt][nt] = (f32x4){0.f, 0.f, 0.f, 0.f};

  for (int k0 = 0; k0 < 1024; k0 += 32) {
    __syncthreads();   // previous compute done before LDS overwrite
#pragma unroll
    for (int g = 0; g < 2; ++g) {
      int grp = w * 2 + g;             // 0..7, each = 16 rows of the tile
      gld_lds16(A + (size_t)(m0 + grp * 16 + lrow) * 1024 + k0 + kseg,
                (char*)Alds + grp * 1024);
      gld_lds16(Bt + (size_t)(n0 + grp * 16 + lrow) * 1024 + k0 + kseg,
                (char*)Blds + grp * 1024);
    }
    __syncthreads();   // barrier drains vmcnt(0): staged data visible
    bf16x8 af[4], bfr[4];
#pragma unroll
    for (int mt = 0; mt < 4; ++mt)
      af[mt] = *(const bf16x8*)(Alds + (wm * 64 + mt * 16 + col) * 32 + quad * 8);
#pragma unroll
    for (int nt = 0; nt < 4; ++nt)
      bfr[nt] = *(const bf16x8*)(Blds + (wn * 64 + nt * 16 + col) * 32 + quad * 8);
#pragma unroll
    for (int mt = 0; mt < 4; ++mt)
#pragma unroll
      for (int nt = 0; nt < 4; ++nt)
        acc[mt][nt] = __builtin_amdgcn_mfma_f32_16x16x32_bf16(af[mt], bfr[nt],
                                                              acc[mt][nt], 0, 0, 0);
  }
}

// GEMM1: Xb @ WqkvT^T + b -> Q (pre-scaled), K (B,H,T,D) and V^T (B,H,D,T)
__global__ __launch_bounds__(256) void gemm_qkv(const u16* __restrict__ X,
                                                const u16* __restrict__ WT,
                                                const float* __restrict__ bias,
                                                u16* __restrict__ Q,
                                                u16* __restrict__ Kc,
                                                u16* __restrict__ Vt) {
  __shared__ __align__(16) u16 Alds[128 * 32];
  __shared__ __align__(16) u16 Blds[128 * 32];
  f32x4 acc[4][4];
  const int m0 = blockIdx.x * 128, n0 = blockIdx.y * 128;
  gemm_tile_acc(X, WT, m0, n0, Alds, Blds, acc);

  const float qscale = 0.18033688011112042f;   // 1/sqrt(D) * log2(e)
  const int tid = threadIdx.x;
  const int w = tid >> 6, lane = tid & 63;
  const int wm = w & 1, wn = w >> 1;
  const int col = lane & 15, quad = lane >> 4;
#pragma unroll
  for (int mt = 0; mt < 4; ++mt)
#pragma unroll
    for (int nt = 0; nt < 4; ++nt) {
      int n = n0 + wn * 64 + nt * 16 + col;
      int s = n >> 10, hh = (n >> 6) & (Hn - 1), d = n & 63;
      int mBase = m0 + wm * 64 + mt * 16 + quad * 4;
      int b = mBase >> 11, t0 = mBase & (Tsz - 1);
      if (s == 2) {
        // V^T: (b,h,d,t) — 4 consecutive t, one 8B store
        u16 vals[4];
#pragma unroll
        for (int r = 0; r < 4; ++r) vals[r] = f2b(acc[mt][nt][r] + bias[n]);
        *(u32x2*)(Vt + ((size_t)(b * Hn + hh) * Dh + d) * Tsz + t0) =
            *(const u32x2*)vals;
      } else {
        const float scl = (s == 0) ? qscale : 1.f;
        u16* dst = (s == 0) ? Q : Kc;
#pragma unroll
        for (int r = 0; r < 4; ++r)
          dst[((size_t)(b * Hn + hh) * Tsz + (t0 + r)) * Dh + d] =
              f2b((acc[mt][nt][r] + bias[n]) * scl);
      }
    }
}

// GEMM2: Ob(8192x1024) @ WprojT(1024x1024)^T + b -> fp32 out (B,T,C)
__global__ __launch_bounds__(256) void gemm_proj(const u16* __restrict__ O,
                                                 const u16* __restrict__ WT,
                                                 const float* __restrict__ bias,
                                                 float* __restrict__ out) {
  __shared__ __align__(16) u16 Alds[128 * 32];
  __shared__ __align__(16) u16 Blds[128 * 32];
  f32x4 acc[4][4];
  const int m0 = blockIdx.x * 128, n0 = blockIdx.y * 128;
  gemm_tile_acc(O, WT, m0, n0, Alds, Blds, acc);

  const int tid = threadIdx.x;
  const int w = tid >> 6, lane = tid & 63;
  const int wm = w & 1, wn = w >> 1;
  const int col = lane & 15, quad = lane >> 4;
#pragma unroll
  for (int mt = 0; mt < 4; ++mt)
#pragma unroll
    for (int nt = 0; nt < 4; ++nt)
#pragma unroll
      for (int r = 0; r < 4; ++r) {
        int m = m0 + wm * 64 + mt * 16 + quad * 4 + r;
        int n = n0 + wn * 64 + nt * 16 + col;
        out[(size_t)m * Csz + n] = acc[mt][nt][r] + bias[n];
      }
}

// ---------------- flash attention, round 6: barrier-free ----------------
// Block = 128 q-rows, 4 waves x 32 rows, fully wave-independent (NO barriers).
// Per 32-key stage: V frags loaded global->VGPR for this stage, K frags
// prefetched global->VGPR for the next (named-var double buffer, 2x unroll).
// P (C-layout -> A-layout) via wave-private padded LDS. Fixed-max softmax
// (Q pre-scaled by 1/sqrt(D)*log2e upstream).
#define PSTR 36

#define ATTN_STAGE(S, KC0, KC1, KC2, KC3, KN0, KN1, KN2, KN3)                   \
  {                                                                             \
    const int s_ = (S);                                                         \
    const u16* vb_ = Vbase + 32 * s_ + v_lane;                                  \
    bf16x8 v0_ = *(const bf16x8*)(vb_);                                         \
    bf16x8 v1_ = *(const bf16x8*)(vb_ + 32768);                                 \
    bf16x8 v2_ = *(const bf16x8*)(vb_ + 65536);                                 \
    bf16x8 v3_ = *(const bf16x8*)(vb_ + 98304);                                 \
    const int sp_ = (s_ + 1 < nst) ? (s_ + 1) : 0;                              \
    const u16* kb_ = Kbase + 2048 * sp_ + k_lane;                               \
    KN0 = *(const bf16x8*)(kb_);                                                \
    KN1 = *(const bf16x8*)(kb_ + 32);                                           \
    KN2 = *(const bf16x8*)(kb_ + 1024);                                         \
    KN3 = *(const bf16x8*)(kb_ + 1056);                                         \
    const f32x4 z_ = (f32x4){0.f, 0.f, 0.f, 0.f};                               \
    f32x4 s00_ = __builtin_amdgcn_mfma_f32_16x16x32_bf16(                       \
        aq01, KC1, __builtin_amdgcn_mfma_f32_16x16x32_bf16(aq00, KC0, z_, 0,0,0), 0,0,0); \
    f32x4 s01_ = __builtin_amdgcn_mfma_f32_16x16x32_bf16(                       \
        aq01, KC3, __builtin_amdgcn_mfma_f32_16x16x32_bf16(aq00, KC2, z_, 0,0,0), 0,0,0); \
    f32x4 s10_ = __builtin_amdgcn_mfma_f32_16x16x32_bf16(                       \
        aq11, KC1, __builtin_amdgcn_mfma_f32_16x16x32_bf16(aq10, KC0, z_, 0,0,0), 0,0,0); \
    f32x4 s11_ = __builtin_amdgcn_mfma_f32_16x16x32_bf16(                       \
        aq11, KC3, __builtin_amdgcn_mfma_f32_16x16x32_bf16(aq10, KC2, z_, 0,0,0), 0,0,0); \
    const bool dg_ = (s_ >= sdiag);                                             \
    const int cb_ = s_ * 32 + col - qbase;                                      \
    _Pragma("unroll")                                                           \
    for (int r = 0; r < 4; ++r) {                                               \
      const int rl0 = w * 32 + quad * 4 + r;                                    \
      const int rl1 = rl0 + 16;                                                 \
      float p0 = exp2f(s00_[r]); if (dg_ && cb_ > rl0) p0 = 0.f;                \
      float p1 = exp2f(s01_[r]); if (dg_ && cb_ + 16 > rl0) p1 = 0.f;           \
      float p2 = exp2f(s10_[r]); if (dg_ && cb_ > rl1) p2 = 0.f;                \
      float p3 = exp2f(s11_[r]); if (dg_ && cb_ + 16 > rl1) p3 = 0.f;           \
      lsum[0][r] += p0 + p1;                                                    \
      lsum[1][r] += p2 + p3;                                                    \
      Ps[rl0 * PSTR + col] = f2b(p0);                                           \
      Ps[rl0 * PSTR + 16 + col] = f2b(p1);                                      \
      Ps[rl1 * PSTR + col] = f2b(p2);                                           \
      Ps[rl1 * PSTR + 16 + col] = f2b(p3);                                      \
    }                                                                           \
    bf16x8 ap0_ = *(const bf16x8*)(&Ps[(w * 32 + col) * PSTR + quad * 8]);      \
    bf16x8 ap1_ = *(const bf16x8*)(&Ps[(w * 32 + 16 + col) * PSTR + quad * 8]); \
    oacc[0][0] = __builtin_amdgcn_mfma_f32_16x16x32_bf16(ap0_, v0_, oacc[0][0], 0,0,0); \
    oacc[0][1] = __builtin_amdgcn_mfma_f32_16x16x32_bf16(ap0_, v1_, oacc[0][1], 0,0,0); \
    oacc[0][2] = __builtin_amdgcn_mfma_f32_16x16x32_bf16(ap0_, v2_, oacc[0][2], 0,0,0); \
    oacc[0][3] = __builtin_amdgcn_mfma_f32_16x16x32_bf16(ap0_, v3_, oacc[0][3], 0,0,0); \
    oacc[1][0] = __builtin_amdgcn_mfma_f32_16x16x32_bf16(ap1_, v0_, oacc[1][0], 0,0,0); \
    oacc[1][1] = __builtin_amdgcn_mfma_f32_16x16x32_bf16(ap1_, v1_, oacc[1][1], 0,0,0); \
    oacc[1][2] = __builtin_amdgcn_mfma_f32_16x16x32_bf16(ap1_, v2_, oacc[1][2], 0,0,0); \
    oacc[1][3] = __builtin_amdgcn_mfma_f32_16x16x32_bf16(ap1_, v3_, oacc[1][3], 0,0,0); \
  }

__global__ __launch_bounds__(256, 3) void attn(const u16* __restrict__ Q,
                                               const u16* __restrict__ Kg,
                                               const u16* __restrict__ Vt,
                                               u16* __restrict__ O) {
  __shared__ __align__(16) u16 Ps[128 * PSTR];     // only LDS use: P transform
  const int qt = (int)(gridDim.x - 1) - blockIdx.x;   // LPT: big tiles first
  const int h = blockIdx.y, b = blockIdx.z;
  const int bh = b * Hn + h;
  const int tid = threadIdx.x, w = tid >> 6, lane = tid & 63;
  const int col = lane & 15, quad = lane >> 4;
  const int qbase = qt * 128;

  const u16* Kbase = Kg + (size_t)bh * Tsz * Dh;      // rows: key, len 64
  const u16* Vbase = Vt + (size_t)bh * Dh * Tsz;      // rows: d, len 2048
  const u16* Qg = Q + ((size_t)bh * Tsz + qbase) * Dh;

  // per-lane fragment offsets
  const int k_lane = col * 64 + quad * 8;     // K frag base (row=col)
  const int v_lane = col * 2048 + quad * 8;   // V^T frag base (row=col)

  // Q fragments (one-time): aq[mt][ks]
  const u16* qb = Qg + (size_t)(w * 32 + col) * 64 + quad * 8;
  bf16x8 aq00 = *(const bf16x8*)(qb);
  bf16x8 aq01 = *(const bf16x8*)(qb + 32);
  bf16x8 aq10 = *(const bf16x8*)(qb + 1024);
  bf16x8 aq11 = *(const bf16x8*)(qb + 1056);

  f32x4 oacc[2][4];
#pragma unroll
  for (int mt = 0; mt < 2; ++mt)
#pragma unroll
    for (int dt = 0; dt < 4; ++dt) oacc[mt][dt] = (f32x4){0.f, 0.f, 0.f, 0.f};
  float lsum[2][4];
#pragma unroll
  for (int mt = 0; mt < 2; ++mt)
#pragma unroll
    for (int r = 0; r < 4; ++r) lsum[mt][r] = 0.f;

  const int nst = 4 * qt + 4;     // 32-key stages (always even)
  const int sdiag = 4 * qt;       // stages >= this need the causal mask

  // preload K frags for stage 0 into set A
  bf16x8 kA0, kA1, kA2, kA3, kB0, kB1, kB2, kB3;
  {
    const u16* kb_ = Kbase + k_lane;
    kA0 = *(const bf16x8*)(kb_);
    kA1 = *(const bf16x8*)(kb_ + 32);
    kA2 = *(const bf16x8*)(kb_ + 1024);
    kA3 = *(const bf16x8*)(kb_ + 1056);
  }

  for (int s = 0; s < nst; s += 2) {
    ATTN_STAGE(s,     kA0, kA1, kA2, kA3, kB0, kB1, kB2, kB3);
    ATTN_STAGE(s + 1, kB0, kB1, kB2, kB3, kA0, kA1, kA2, kA3);
  }

  // one-time l reduction across the 16 col-lanes (quad preserved by xor<16)
#pragma unroll
  for (int mt = 0; mt < 2; ++mt)
#pragma unroll
    for (int r = 0; r < 4; ++r) {
      float v = lsum[mt][r];
#pragma unroll
      for (int off = 1; off < 16; off <<= 1) v += __shfl_xor(v, off);
      lsum[mt][r] = v;
    }

  // epilogue: O[b, t, h, d] = oacc / l   (bf16, (B,T,H,D) row-major = (B,T,C))
#pragma unroll
  for (int mt = 0; mt < 2; ++mt)
#pragma unroll
    for (int r = 0; r < 4; ++r) {
      float inv = 1.0f / lsum[mt][r];
      int rg = qbase + w * 32 + mt * 16 + quad * 4 + r;
#pragma unroll
      for (int dt = 0; dt < 4; ++dt) {
        int d = dt * 16 + col;
        O[(((size_t)b * Tsz + rg) * Hn + h) * Dh + d] = f2b(oacc[mt][dt][r] * inv);
      }
    }
}

extern "C" void kernel_launch(void* const* d_in, const int* in_sizes, int n_in,
                              void* d_out, int out_size, void* d_ws, size_t ws_size,
                              hipStream_t stream) {
  const float* x      = (const float*)d_in[0];
  const float* w_qkv  = (const float*)d_in[1];
  const float* b_qkv  = (const float*)d_in[2];
  const float* w_proj = (const float*)d_in[3];
  const float* b_proj = (const float*)d_in[4];
  float* out = (float*)d_out;

  // workspace layout (u16 elements), total 72 MB
  u16* Xb     = (u16*)d_ws;                          // 8192*1024
  u16* WqkvT  = Xb + (size_t)8192 * 1024;            // 3072*1024
  u16* WprojT = WqkvT + (size_t)3072 * 1024;         // 1024*1024
  u16* Qb     = WprojT + (size_t)1024 * 1024;        // 8192*1024 (pre-scaled)
  u16* Kb     = Qb + (size_t)8192 * 1024;            // 8192*1024
  u16* Ob     = Kb + (size_t)8192 * 1024;            // 8192*1024 (B,T,H,D)
  // d_out doubles as scratch: V^T (B,H,D,T) bf16, 16 MB; overwritten by gemm_proj
  u16* Vtb    = (u16*)d_out;                         // 8192*1024

  cvt_f32_bf16<<<4096, 256, 0, stream>>>(x, Xb);
  cvt_transpose<<<dim3(16, 48), 256, 0, stream>>>(w_qkv, WqkvT, 1024, 3072);
  cvt_transpose<<<dim3(16, 16), 256, 0, stream>>>(w_proj, WprojT, 1024, 1024);
  gemm_qkv<<<dim3(64, 24), 256, 0, stream>>>(Xb, WqkvT, b_qkv, Qb, Kb, Vtb);
  attn<<<dim3(16, 16, 4), 256, 0, stream>>>(Qb, Kb, Vtb, Ob);
  gemm_proj<<<dim3(64, 8), 256, 0, stream>>>(Ob, WprojT, b_proj, out);
}